// Round 8
// baseline (468.036 us; speedup 1.0000x reference)
//
#include <hip/hip_runtime.h>

namespace {
constexpr int Bn = 2, Dn = 48, Hn = 320, Wn = 640;
constexpr int R = 2, K = 5, K2 = 25, C3 = 75;
constexpr int TW = 64, TH = 4;
constexpr int NT = TW * TH;      // 256 threads
}

// out[b,d,h,w] = sum_{ij in 5x5} w0*x[d] + w1*x[d-1] + w2*x[d+1], zero-padded.
// Sg(p) = sum_ij wg[ij]*win_p[ij]; out[d] = S0(d)+S1(d-1)+S2(d+1)
//   -> ONE 25-elem window per plane + 2 carry scalars.
//
// r8: NO LDS, NO BARRIERS. The whole x volume is 39 MB (L3-resident); a
// tile's rows are L1/L2-resident. Guide common-mistake #7: don't LDS-stage
// what cache-fits. Each thread reads its own 5x5 window with 25 coalesced
// global_load_dword per plane (per (i,j) tap the wave's 64 lanes are
// consecutive -> one 256B request, L1-hit across overlapping taps).
// This moves delivery off the LDS pipe (was ~72us/pass, the largest pipe,
// plus staging writes plus 24 barrier rendezvous) onto the TA/L1 path
// (~50us), and removes ALL inter-wave coupling. History: LDS-pipeline
// variants r0/r5/r6 = 170/167/176us; best LDS version r4 = 126us; deeper
// DMA lookahead regressed (queue back-pressure at ~40 outstanding/wave).
//
// Edges: column base cb = clamp(gw-2, 0, W-5) keeps all 5 taps in-row;
// residual shift s = (gw-2)-cb is folded into the WEIGHTS at load time
// (wr[k] = w[k-s], 0 outside) -> per-lane shifted weight addresses in the
// prologue, zero steady-state cost, no per-tap address clamps. Row-OOB
// taps weight-zeroed with row-clamped pointers (valid address, 0 weight).
//
// LAUNCH BOUNDS: (256,2) and nothing tighter — (256,4) capped VGPR at 64,
// spilled wr[75], 13x traffic (round-1 disaster). Register budget binds.
__global__ __launch_bounds__(NT, 2)
void lga_pass(const float* __restrict__ x, const float* __restrict__ wt,
              float* __restrict__ out) {
    const int tx = threadIdx.x;          // 0..63 (w)
    const int ty = threadIdx.y;          // 0..3  (h)

    const int gw = blockIdx.x * TW + tx;
    const int gh = blockIdx.y * TH + ty;
    const int b = blockIdx.z;

    const size_t ps = (size_t)Hn * Wn;

    // column window base (all 5 taps in-row), shift folded into weights
    const int cb = min(max(gw - R, 0), Wn - K);   // [0, 635]
    const int s = (gw - R) - cb;                  // -2..2, nonzero only at w-edges

    // ---- 75 per-pixel guidance weights -> registers, column-shifted by s,
    //      row-OOB taps zeroed (replaces all spatial zero-padding) ----
    float wr[C3];
    {
        const float* wp = wt + (size_t)b * C3 * ps + (size_t)gh * Wn + gw;
#pragma unroll
        for (int i = 0; i < K; ++i) {
            const int hh = gh + i - R;
            const bool vh = (hh >= 0) && (hh < Hn);
#pragma unroll
            for (int k = 0; k < K; ++k) {
                const int jj = k - s;             // original tap col index
                const bool ok = vh && (jj >= 0) && (jj < K);
                const int c = i * K + jj;
                float w0 = 0.f, w1 = 0.f, w2 = 0.f;
                if (ok) {
                    w0 = wp[(size_t)c * ps];
                    w1 = wp[(size_t)(K2 + c) * ps];
                    w2 = wp[(size_t)(2 * K2 + c) * ps];
                }
                wr[i * K + k] = w0;
                wr[K2 + i * K + k] = w1;
                wr[2 * K2 + i * K + k] = w2;
            }
        }
    }

    // ---- 5 row base pointers (row-clamped), advanced by ps per plane ----
    const float* xb = x + (size_t)b * Dn * ps;
    const float* p0 = xb + (size_t)min(max(gh - 2, 0), Hn - 1) * Wn + cb;
    const float* p1 = xb + (size_t)min(max(gh - 1, 0), Hn - 1) * Wn + cb;
    const float* p2 = xb + (size_t)gh * Wn + cb;
    const float* p3 = xb + (size_t)min(gh + 1, Hn - 1) * Wn + cb;
    const float* p4 = xb + (size_t)min(gh + 2, Hn - 1) * Wn + cb;

    float* op = out + (size_t)b * Dn * ps + (size_t)gh * Wn + gw;

    float carry = 0.f, s1prev = 0.f;

#pragma unroll 1
    for (int d = 0; d < Dn; ++d) {
        // 25 coalesced global loads (offsets 0..16B off 5 row pointers);
        // issued as a batch so the compiler inserts counted vmcnt before
        // the first consuming FMA (ILP within the step, TLP across waves).
        float v[K][K];
#pragma unroll
        for (int k = 0; k < K; ++k) v[0][k] = p0[k];
#pragma unroll
        for (int k = 0; k < K; ++k) v[1][k] = p1[k];
#pragma unroll
        for (int k = 0; k < K; ++k) v[2][k] = p2[k];
#pragma unroll
        for (int k = 0; k < K; ++k) v[3][k] = p3[k];
#pragma unroll
        for (int k = 0; k < K; ++k) v[4][k] = p4[k];

        float S0 = 0.f, S1 = 0.f, S2 = 0.f;
#pragma unroll
        for (int i = 0; i < K; ++i)
#pragma unroll
            for (int k = 0; k < K; ++k) {
                const float vv = v[i][k];
                S0 += wr[i * K + k] * vv;
                S1 += wr[K2 + i * K + k] * vv;
                S2 += wr[2 * K2 + i * K + k] * vv;
            }

        if (d > 0) { *op = carry + S2; op += ps; }
        carry = S0 + s1prev;
        s1prev = S1;

        p0 += ps; p1 += ps; p2 += ps; p3 += ps; p4 += ps;
    }
    // out[D-1] = S0(D-1) + S1(D-2)   (S2 of plane D is zero)
    *op = carry;
}

extern "C" void kernel_launch(void* const* d_in, const int* in_sizes, int n_in,
                              void* d_out, int out_size, void* d_ws, size_t ws_size,
                              hipStream_t stream) {
    const float* x = (const float*)d_in[0];
    const float* w = (const float*)d_in[1];
    // d_in[2] = radius (always 2 here; compile-time constant)
    float* out = (float*)d_out;
    float* tmp = (float*)d_ws;   // intermediate y (78.6 MB)

    dim3 block(TW, TH, 1);
    dim3 grid(Wn / TW, Hn / TH, Bn);

    lga_pass<<<grid, block, 0, stream>>>(x, w, tmp);
    lga_pass<<<grid, block, 0, stream>>>(tmp, w, out);
}